// Round 11
// baseline (267.330 us; speedup 1.0000x reference)
//
#include <hip/hip_runtime.h>

typedef short bf16x8 __attribute__((ext_vector_type(8)));
typedef float f32x4  __attribute__((ext_vector_type(4)));
typedef unsigned int u32x4 __attribute__((ext_vector_type(4)));

#define MFMA16(a,b,c) __builtin_amdgcn_mfma_f32_16x16x32_bf16(a,b,c,0,0,0)
#define SCALE_F 0.17677669529663687f
#define LOG2E   1.4426950408889634f

union FragU { u32x4 u4; unsigned int u[4]; bf16x8 f; };
struct WPair { bf16x8 h, l; };

__device__ __forceinline__ float fexp2(float x){ return __builtin_amdgcn_exp2f(x); }
__device__ __forceinline__ float frcp(float x){ return __builtin_amdgcn_rcpf(x); }

__device__ __forceinline__ unsigned short rne1(float x){
  unsigned int u = __float_as_uint(x);
  return (unsigned short)((u + 0x7fffu + ((u>>16)&1u)) >> 16);
}
__device__ __forceinline__ void split1(float x, unsigned short& h, unsigned short& l){
  h = rne1(x);
  float hf = __uint_as_float((unsigned)h<<16);
  l = rne1(x - hf);
}
// truncated-hi + rne-residual
__device__ __forceinline__ void trsplit(float x, unsigned short& h, unsigned short& l){
  unsigned int u = __float_as_uint(x);
  h = (unsigned short)(u>>16);
  l = rne1(x - __uint_as_float(u & 0xffff0000u));
}
// packed hi/lo u32: [31:16]=trunc-hi bf16, [15:0]=bf16(residual)
__device__ __forceinline__ unsigned int pk32(float x){
  unsigned int u = __float_as_uint(x);
  unsigned int h = u & 0xffff0000u;
  float r = x - __uint_as_float(h);
  return h | (__float_as_uint(r) >> 16);
}
__device__ __forceinline__ void unpack8(const unsigned int* ur, FragU& hi, FragU& lo){
  #pragma unroll
  for (int i=0;i<4;++i){
    hi.u[i] = __builtin_amdgcn_perm(ur[2*i+1], ur[2*i], 0x07060302u);
    lo.u[i] = __builtin_amdgcn_perm(ur[2*i+1], ur[2*i], 0x05040100u);
  }
}
__device__ __forceinline__ f32x4 mfma3(bf16x8 ah, bf16x8 al, bf16x8 bh, bf16x8 bl, f32x4 c){
  c = MFMA16(ah, bh, c);
  c = MFMA16(al, bh, c);
  c = MFMA16(ah, bl, c);
  return c;
}

// ws: frag(t,l) at (t*64+l)*8 u32: 4 hi, 4 lo. tiles 0-1 wfuseT(x LOG2E), 2-3 wv,
// 4-9 gwih (r,z x LOG2E; n x 2LOG2E), 10-15 gwhh (same scaling).
__device__ __forceinline__ void store_frag(unsigned int* ws, int t, int l, const float* v){
  FragU hh, ll;
  #pragma unroll
  for (int i=0;i<4;++i){
    unsigned short h0,l0,h1,l1;
    split1(v[2*i],   h0, l0);
    split1(v[2*i+1], h1, l1);
    hh.u[i] = (unsigned)h0 | ((unsigned)h1<<16);
    ll.u[i] = (unsigned)l0 | ((unsigned)l1<<16);
  }
  *(u32x4*)(ws + (size_t)(t*64+l)*8)     = hh.u4;
  *(u32x4*)(ws + (size_t)(t*64+l)*8 + 4) = ll.u4;
}
__device__ __forceinline__ WPair load_pre(const unsigned int* ws, int t, int l){
  const unsigned int* p = ws + (size_t)(t*64+l)*8;
  FragU a,b; a.u4 = *(const u32x4*)p; b.u4 = *(const u32x4*)(p+4);
  WPair r; r.h = a.f; r.l = b.f; return r;
}

__global__ __launch_bounds__(1024)
void prep_kernel(const float* __restrict__ wq,
                 const float* __restrict__ wk,
                 const float* __restrict__ wv,
                 const float* __restrict__ gwih,
                 const float* __restrict__ gwhh,
                 unsigned int* __restrict__ ws)
{
  __shared__ float pw[1024], pk2[1024], pf[1024];
  const int tid = threadIdx.x;
  pw[tid]  = wq[tid];
  pk2[tid] = wk[tid];
  __syncthreads();
  {
    int d = tid>>5, c = tid&31;
    float acc = 0.f;
    #pragma unroll
    for (int dp=0; dp<32; ++dp) acc = fmaf(pw[dp*32+d], pk2[dp*32+c], acc);
    pf[d*32+c] = acc * (SCALE_F * LOG2E);
  }
  __syncthreads();
  const int l = tid & 63, g = l>>4, m = l&15;
  float v[8];
  if (tid < 128){
    int t = tid>>6;   // 0..1 : wfuse tiles
    #pragma unroll
    for (int j=0;j<8;++j) v[j] = pf[(t*16+m)*32 + 8*g + j];
    store_frag(ws, t, l, v);
  } else {
    int tile = 2 + ((tid-128)>>6);   // 2..15
    const float* src; float sc = 1.f;
    if (tile < 4)       { src = wv   + (tile-2)*16*32; }
    else if (tile < 10) { src = gwih + (tile-4)*16*32; sc = (tile>=8)  ? 2.f*LOG2E : LOG2E; }
    else                { src = gwhh + (tile-10)*16*32; sc = (tile>=14) ? 2.f*LOG2E : LOG2E; }
    #pragma unroll
    for (int j=0;j<8;++j) v[j] = src[m*32 + 8*g + j] * sc;
    store_frag(ws, tile, l, v);
  }
}

// LDS map (12288 B / block, 1 wave), reused every chunk:
//  R0 @0 (8192): phase A: x packed u32 [4 bt][16 tok][128B]: bt*2048+tok*128+4d, XOR((tok&7)<<4)
//     iters: S @0 [16 row][128B] packed (row=4b+s), U @2048 same, ATH @4096, ATL @4608, ZPG @5120 (32B)
//  VT @8192 (4096): single-bf16 v^T [32 d][128B]: d*128 + 2*(bt*16+tok), XOR((d&7)<<4)
#define UOF 2048
#define ATO 4096
#define ZPGO 5120
#define VTO 8192

__global__ __launch_bounds__(64, 2)
void slotattn_mfma(const float* __restrict__ latent,
                   const float* __restrict__ slot_mu,
                   const float* __restrict__ w_in,
                   const float* __restrict__ b_in,
                   const float* __restrict__ ln_g,
                   const float* __restrict__ ln_b,
                   const float* __restrict__ gbih,
                   const float* __restrict__ gbhh,
                   const unsigned int* __restrict__ ws,
                   float* __restrict__ out,
                   int nch)
{
  __shared__ __attribute__((aligned(16))) char sw[12288];
  const int l = threadIdx.x & 63;
  const int g = l >> 4;
  const int m = l & 15;
  const int xorm = (m & 7) << 4;

  for (int ch = blockIdx.x; ch < nch; ch += gridDim.x){
    const int batch0 = ch * 4;

    // ---- Phase A: latent -> proj -> LN -> packed x to LDS (thread = batch g, token m) ----
    {
      const float* latp = latent + (size_t)(batch0 + g) * 128 + m;
      float c[8];
      #pragma unroll
      for (int cc=0; cc<8; ++cc) c[cc] = latp[cc*16];
      float xr[32];
      #pragma unroll
      for (int d=0; d<32; ++d){
        float acc = b_in[d];
        #pragma unroll
        for (int cc=0; cc<8; ++cc) acc = fmaf(c[cc], w_in[d*8+cc], acc);
        xr[d] = acc;
      }
      float mu = 0.f;
      #pragma unroll
      for (int d=0; d<32; ++d) mu += xr[d];
      mu *= 0.03125f;
      float var = 0.f;
      #pragma unroll
      for (int d=0; d<32; ++d){ float t = xr[d]-mu; var = fmaf(t,t,var); }
      var *= 0.03125f;
      float rs = rsqrtf(var + 1e-5f);
      char* dst = sw + g*2048 + m*128;
      #pragma unroll
      for (int q=0; q<8; ++q){
        u32x4 pv;
        #pragma unroll
        for (int i=0;i<4;++i){
          int d = 4*q+i;
          pv[i] = pk32((xr[d]-mu)*rs*ln_g[d] + ln_b[d]);
        }
        *(u32x4*)(dst + ((q*16) ^ xorm)) = pv;
      }
    }
    asm volatile("" ::: "memory");

    // ---- Phase C: kq = x@wfuse, v = x@wv^T ; kq -> R0 (packed), v^T -> VT (single bf16) ----
    FragU kqh[4], kql[4];
    {
      unsigned int xr8[4][8];
      #pragma unroll
      for (int bt=0; bt<4; ++bt){
        const char* base = sw + bt*2048 + m*128;
        *(u32x4*)&xr8[bt][0] = *(const u32x4*)(base + ((g*32)    ^ xorm));
        *(u32x4*)&xr8[bt][4] = *(const u32x4*)(base + ((g*32+16) ^ xorm));
      }
      asm volatile("" ::: "memory");
      WPair wf0 = load_pre(ws, 0, l), wf1 = load_pre(ws, 1, l);
      WPair wv0 = load_pre(ws, 2, l), wv1 = load_pre(ws, 3, l);
      #pragma unroll
      for (int bt=0; bt<4; ++bt){
        FragU xh, xl; unpack8(xr8[bt], xh, xl);
        f32x4 z = {0,0,0,0};
        f32x4 k0 = mfma3(xh.f, xl.f, wf0.h, wf0.l, z);
        f32x4 k1 = mfma3(xh.f, xl.f, wf1.h, wf1.l, z);
        f32x4 v0 = mfma3(xh.f, xl.f, wv0.h, wv0.l, z);
        f32x4 v1 = mfma3(xh.f, xl.f, wv1.h, wv1.l, z);
        #pragma unroll
        for (int r=0; r<4; ++r){
          int row = 4*g + r;
          int xr_ = (row & 7) << 4;
          char* kb = sw + bt*2048 + row*128;
          *(unsigned int*)(kb + ((4*m)      ^ xr_)) = pk32(k0[r]);
          *(unsigned int*)(kb + ((4*(m+16)) ^ xr_)) = pk32(k1[r]);
        }
        ushort4 pv0, pv1;
        pv0.x=rne1(v0[0]); pv0.y=rne1(v0[1]); pv0.z=rne1(v0[2]); pv0.w=rne1(v0[3]);
        pv1.x=rne1(v1[0]); pv1.y=rne1(v1[1]); pv1.z=rne1(v1[2]); pv1.w=rne1(v1[3]);
        *(ushort4*)(sw + VTO + m*128      + ((bt*32 + 8*g) ^ xorm)) = pv0;
        *(ushort4*)(sw + VTO + (m+16)*128 + ((bt*32 + 8*g) ^ xorm)) = pv1;
      }
      asm volatile("" ::: "memory");
      // one-time kq B-frags -> registers
      #pragma unroll
      for (int bt=0; bt<4; ++bt){
        const char* base = sw + bt*2048 + m*128;
        unsigned int kr[8];
        *(u32x4*)&kr[0] = *(const u32x4*)(base + ((g*32)    ^ xorm));
        *(u32x4*)&kr[4] = *(const u32x4*)(base + ((g*32+16) ^ xorm));
        unpack8(kr, kqh[bt], kql[bt]);
      }
    }
    asm volatile("" ::: "memory");

    // ---- zero page + h init (R0 region now free) ----
    if (l < 2){ u32x4 z = {0,0,0,0}; *(u32x4*)(sw + ZPGO + l*16) = z; }
    float hreg[8];   // hreg[4T+r] = h[(b=g,s=r)][d=m+16T]
    #pragma unroll
    for (int T=0; T<2; ++T){
      #pragma unroll
      for (int r=0; r<4; ++r){
        float v = slot_mu[r*32 + m + 16*T];
        hreg[4*T+r] = v;
        int row = 4*g + r;
        *(unsigned int*)(sw + row*128 + ((4*(m+16*T)) ^ ((row&7)<<4))) = pk32(v);
      }
    }

    // ---- GRU weight fragments + pre-scaled biases (reloaded per chunk, L2-hot) ----
    WPair wihf[6], whhf[6];
    float bihl[6], bhhl[6];
    #pragma unroll
    for (int t=0; t<6; ++t){
      wihf[t] = load_pre(ws, 4+t, l);
      whhf[t] = load_pre(ws, 10+t, l);
      float bsc = (t < 4) ? LOG2E : 2.f*LOG2E;
      bihl[t] = gbih[t*16 + m] * bsc;
      bhhl[t] = gbhh[t*16 + m] * bsc;
    }

    for (int it=0; it<3; ++it){
      asm volatile("" ::: "memory");
      // slots A-frags
      unsigned int sr[8];
      {
        const char* sb = sw + m*128;
        *(u32x4*)&sr[0] = *(const u32x4*)(sb + ((g*32)    ^ xorm));
        *(u32x4*)&sr[4] = *(const u32x4*)(sb + ((g*32+16) ^ xorm));
      }
      FragU sh, sl; unpack8(sr, sh, sl);

      // logits (exp2-domain) = slots @ kq^T ; keep batch g
      f32x4 ls = {0,0,0,0};
      #pragma unroll
      for (int bt=0; bt<4; ++bt){
        f32x4 z = {0,0,0,0};
        f32x4 la = mfma3(sh.f, sl.f, kqh[bt].f, kql[bt].f, z);
        if (bt==0) ls = la;
        else {
          bool take = (g==bt);
          #pragma unroll
          for (int c2=0;c2<4;++c2) ls[c2] = take ? la[c2] : ls[c2];
        }
      }
      // softmax over slots (batch g, token m) -> ATH/ATL u16
      {
        float mx = fmaxf(fmaxf(ls[0],ls[1]), fmaxf(ls[2],ls[3]));
        float e0=fexp2(ls[0]-mx), e1=fexp2(ls[1]-mx), e2=fexp2(ls[2]-mx), e3=fexp2(ls[3]-mx);
        float inv = frcp(e0+e1+e2+e3);
        float ev[4] = { e0*inv, e1*inv, e2*inv, e3*inv };
        #pragma unroll
        for (int s=0; s<4; ++s){
          unsigned short h, lo;
          trsplit(ev[s], h, lo);
          *(unsigned short*)(sw + ATO       + g*128 + s*32 + 2*m) = h;
          *(unsigned short*)(sw + ATO + 512 + g*128 + s*32 + 2*m) = lo;
        }
      }
      asm volatile("" ::: "memory");

      // updates^T = v^T @ attn^T : 2 batches packed per MFMA (K=32), v single-bf16
      FragU abh[2], abl[2];
      #pragma unroll
      for (int inst=0; inst<2; ++inst){
        int bk = inst*2 + (g>>1);
        bool match = ((m>>2) == bk);
        int aoff = (m>>2)*128 + (m&3)*32 + (g&1)*16;
        abh[inst].u4 = *(const u32x4*)(match ? (sw + ATO       + aoff) : (sw + ZPGO));
        abl[inst].u4 = *(const u32x4*)(match ? (sw + ATO + 512 + aoff) : (sw + ZPGO));
      }
      f32x4 uT[2];
      #pragma unroll
      for (int T=0; T<2; ++T){
        f32x4 acc = {0,0,0,0};
        #pragma unroll
        for (int inst=0; inst<2; ++inst){
          int bk = inst*2 + (g>>1);
          FragU va;
          va.u4 = *(const u32x4*)(sw + VTO + (16*T+m)*128 + ((bk*32 + (g&1)*16) ^ xorm));
          acc = MFMA16(va.f, abh[inst].f, acc);
          acc = MFMA16(va.f, abl[inst].f, acc);
        }
        uT[T] = acc;
      }
      // u writeback: lane holds upd[(b,s)=m][d=16T+4g+r] -> packed u32, b128
      #pragma unroll
      for (int T=0; T<2; ++T){
        u32x4 up;
        #pragma unroll
        for (int r=0;r<4;++r) up[r] = pk32(uT[T][r]);
        *(u32x4*)(sw + UOF + m*128 + ((64*T + 16*g) ^ xorm)) = up;
      }
      asm volatile("" ::: "memory");

      // u A-frags
      unsigned int ur2[8];
      {
        const char* ub = sw + UOF + m*128;
        *(u32x4*)&ur2[0] = *(const u32x4*)(ub + ((g*32)    ^ xorm));
        *(u32x4*)&ur2[4] = *(const u32x4*)(ub + ((g*32+16) ^ xorm));
      }
      FragU uh, ul; unpack8(ur2, uh, ul);

      // GRU per output half T (tiles t = {T, 2+T, 4+T})
      bool last = (it==2);
      #pragma unroll
      for (int T=0; T<2; ++T){
        f32x4 gi3[3], gh3[3];
        #pragma unroll
        for (int s3=0; s3<3; ++s3){
          int t = 2*s3 + T;
          f32x4 ci = { bihl[t], bihl[t], bihl[t], bihl[t] };
          gi3[s3] = mfma3(uh.f, ul.f, wihf[t].h, wihf[t].l, ci);
          f32x4 ch = { bhhl[t], bhhl[t], bhhl[t], bhhl[t] };
          gh3[s3] = mfma3(sh.f, sl.f, whhf[t].h, whhf[t].l, ch);
        }
        #pragma unroll
        for (int r=0; r<4; ++r){
          // pre-activations already in exp2 domain (r,z x LOG2E; n x 2LOG2E)
          float rr = frcp(1.f + fexp2(-(gi3[0][r] + gh3[0][r])));
          float zz = frcp(1.f + fexp2(-(gi3[1][r] + gh3[1][r])));
          float pre = fmaf(rr, gh3[2][r], gi3[2][r]);
          float nn = fmaf(-2.f, frcp(fexp2(pre) + 1.f), 1.f);
          int d = m + 16*T;
          float hval = hreg[4*T+r];
          float hnew = fmaf(zz, hval - nn, nn);
          hreg[4*T+r] = hnew;
          if (last){
            out[(size_t)(batch0+g)*128 + r*32 + d] = hnew;
          } else {
            int row = 4*g + r;
            *(unsigned int*)(sw + row*128 + ((4*d) ^ ((row&7)<<4))) = pk32(hnew);
          }
        }
      }
    }
    asm volatile("" ::: "memory");
  }
}

extern "C" void kernel_launch(void* const* d_in, const int* in_sizes, int n_in,
                              void* d_out, int out_size, void* d_ws, size_t ws_size,
                              hipStream_t stream) {
  const float* latent  = (const float*)d_in[0];
  const float* slot_mu = (const float*)d_in[1];
  const float* w_in    = (const float*)d_in[2];
  const float* b_in    = (const float*)d_in[3];
  const float* ln_g    = (const float*)d_in[4];
  const float* ln_b    = (const float*)d_in[5];
  const float* wq      = (const float*)d_in[6];
  const float* wk      = (const float*)d_in[7];
  const float* wv      = (const float*)d_in[8];
  const float* gwih    = (const float*)d_in[9];
  const float* gwhh    = (const float*)d_in[10];
  const float* gbih    = (const float*)d_in[11];
  const float* gbhh    = (const float*)d_in[12];
  float* out = (float*)d_out;
  unsigned int* ws = (unsigned int*)d_ws;

  prep_kernel<<<1, 1024, 0, stream>>>(wq, wk, wv, gwih, gwhh, ws);

  const int B = in_sizes[0] >> 7;    // 65536
  const int nch = B >> 2;            // 16384 chunks of 4 batches
  int grid = 13 * 256;               // LDS-resident max: 13 blocks/CU x 256 CUs
  if (grid > nch) grid = nch;
  slotattn_mfma<<<grid, 64, 0, stream>>>(latent, slot_mu, w_in, b_in, ln_g, ln_b,
                                         gbih, gbhh, ws, out, nch);
}

// Round 12
// 90.447 us; speedup vs baseline: 2.9557x; 2.9557x over previous
//
#include <hip/hip_runtime.h>

typedef short bf16x8 __attribute__((ext_vector_type(8)));
typedef float f32x4  __attribute__((ext_vector_type(4)));
typedef unsigned int u32x4 __attribute__((ext_vector_type(4)));

#define MFMA16(a,b,c) __builtin_amdgcn_mfma_f32_16x16x32_bf16(a,b,c,0,0,0)
#define SCALE_F 0.17677669529663687f
#define LOG2E   1.4426950408889634f

union FragU { u32x4 u4; unsigned int u[4]; bf16x8 f; };
struct WPair { bf16x8 h, l; };

__device__ __forceinline__ float fexp2(float x){ return __builtin_amdgcn_exp2f(x); }
__device__ __forceinline__ float frcp(float x){ return __builtin_amdgcn_rcpf(x); }

__device__ __forceinline__ unsigned short rne1(float x){
  unsigned int u = __float_as_uint(x);
  return (unsigned short)((u + 0x7fffu + ((u>>16)&1u)) >> 16);
}
__device__ __forceinline__ void split1(float x, unsigned short& h, unsigned short& l){
  h = rne1(x);
  float hf = __uint_as_float((unsigned)h<<16);
  l = rne1(x - hf);
}
// truncated-hi + rne-residual
__device__ __forceinline__ void trsplit(float x, unsigned short& h, unsigned short& l){
  unsigned int u = __float_as_uint(x);
  h = (unsigned short)(u>>16);
  l = rne1(x - __uint_as_float(u & 0xffff0000u));
}
// packed hi/lo u32: [31:16]=trunc-hi bf16, [15:0]=bf16(residual)
__device__ __forceinline__ unsigned int pk32(float x){
  unsigned int u = __float_as_uint(x);
  unsigned int h = u & 0xffff0000u;
  float r = x - __uint_as_float(h);
  return h | (__float_as_uint(r) >> 16);
}
__device__ __forceinline__ void unpack8(const unsigned int* ur, FragU& hi, FragU& lo){
  #pragma unroll
  for (int i=0;i<4;++i){
    hi.u[i] = __builtin_amdgcn_perm(ur[2*i+1], ur[2*i], 0x07060302u);
    lo.u[i] = __builtin_amdgcn_perm(ur[2*i+1], ur[2*i], 0x05040100u);
  }
}
__device__ __forceinline__ f32x4 mfma3(bf16x8 ah, bf16x8 al, bf16x8 bh, bf16x8 bl, f32x4 c){
  c = MFMA16(ah, bh, c);
  c = MFMA16(al, bh, c);
  c = MFMA16(ah, bl, c);
  return c;
}

// ws: frag(t,l) at (t*64+l)*8 u32: 4 hi, 4 lo. tiles 0-1 wfuseT(x LOG2E), 2-3 wv,
// 4-9 gwih (r,z x LOG2E; n x 2LOG2E), 10-15 gwhh (same scaling).
__device__ __forceinline__ void store_frag(unsigned int* ws, int t, int l, const float* v){
  FragU hh, ll;
  #pragma unroll
  for (int i=0;i<4;++i){
    unsigned short h0,l0,h1,l1;
    split1(v[2*i],   h0, l0);
    split1(v[2*i+1], h1, l1);
    hh.u[i] = (unsigned)h0 | ((unsigned)h1<<16);
    ll.u[i] = (unsigned)l0 | ((unsigned)l1<<16);
  }
  *(u32x4*)(ws + (size_t)(t*64+l)*8)     = hh.u4;
  *(u32x4*)(ws + (size_t)(t*64+l)*8 + 4) = ll.u4;
}
__device__ __forceinline__ WPair load_pre(const unsigned int* ws, int t, int l){
  const unsigned int* p = ws + (size_t)(t*64+l)*8;
  FragU a,b; a.u4 = *(const u32x4*)p; b.u4 = *(const u32x4*)(p+4);
  WPair r; r.h = a.f; r.l = b.f; return r;
}

__global__ __launch_bounds__(1024)
void prep_kernel(const float* __restrict__ wq,
                 const float* __restrict__ wk,
                 const float* __restrict__ wv,
                 const float* __restrict__ gwih,
                 const float* __restrict__ gwhh,
                 unsigned int* __restrict__ ws)
{
  __shared__ float pw[1024], pk2[1024], pf[1024];
  const int tid = threadIdx.x;
  pw[tid]  = wq[tid];
  pk2[tid] = wk[tid];
  __syncthreads();
  {
    int d = tid>>5, c = tid&31;
    float acc = 0.f;
    #pragma unroll
    for (int dp=0; dp<32; ++dp) acc = fmaf(pw[dp*32+d], pk2[dp*32+c], acc);
    pf[d*32+c] = acc * (SCALE_F * LOG2E);
  }
  __syncthreads();
  const int l = tid & 63, g = l>>4, m = l&15;
  float v[8];
  if (tid < 128){
    int t = tid>>6;   // 0..1 : wfuse tiles
    #pragma unroll
    for (int j=0;j<8;++j) v[j] = pf[(t*16+m)*32 + 8*g + j];
    store_frag(ws, t, l, v);
  } else {
    int tile = 2 + ((tid-128)>>6);   // 2..15
    const float* src; float sc = 1.f;
    if (tile < 4)       { src = wv   + (tile-2)*16*32; }
    else if (tile < 10) { src = gwih + (tile-4)*16*32; sc = (tile>=8)  ? 2.f*LOG2E : LOG2E; }
    else                { src = gwhh + (tile-10)*16*32; sc = (tile>=14) ? 2.f*LOG2E : LOG2E; }
    #pragma unroll
    for (int j=0;j<8;++j) v[j] = src[m*32 + 8*g + j] * sc;
    store_frag(ws, tile, l, v);
  }
}

// LDS map (12288 B / block, 1 wave):
//  R0 @0 (8192): phase A: x packed u32 [4 bt][16 tok][128B]: bt*2048+tok*128+4d, XOR((tok&7)<<4)
//     iters: S @0 [16 row][128B] packed (row=4b+s), U @2048 same, ATH @4096, ATL @4608, ZPG @5120 (32B)
//  VT @8192 (4096): single-bf16 v^T [32 d][128B]: d*128 + 2*(bt*16+tok), XOR((d&7)<<4)
#define UOF 2048
#define ATO 4096
#define ZPGO 5120
#define VTO 8192

__global__ __launch_bounds__(64, 2)
void slotattn_mfma(const float* __restrict__ latent,
                   const float* __restrict__ slot_mu,
                   const float* __restrict__ w_in,
                   const float* __restrict__ b_in,
                   const float* __restrict__ ln_g,
                   const float* __restrict__ ln_b,
                   const float* __restrict__ gbih,
                   const float* __restrict__ gbhh,
                   const unsigned int* __restrict__ ws,
                   float* __restrict__ out)
{
  __shared__ __attribute__((aligned(16))) char sw[12288];
  const int l = threadIdx.x & 63;
  const int g = l >> 4;
  const int m = l & 15;
  const int batch0 = blockIdx.x * 4;
  const int xorm = (m & 7) << 4;

  // ---- Phase A: latent -> proj -> LN -> packed x to LDS (thread = batch g, token m) ----
  {
    const float* latp = latent + (size_t)(batch0 + g) * 128 + m;
    float c[8];
    #pragma unroll
    for (int cc=0; cc<8; ++cc) c[cc] = latp[cc*16];
    float xr[32];
    #pragma unroll
    for (int d=0; d<32; ++d){
      float acc = b_in[d];
      #pragma unroll
      for (int cc=0; cc<8; ++cc) acc = fmaf(c[cc], w_in[d*8+cc], acc);
      xr[d] = acc;
    }
    float mu = 0.f;
    #pragma unroll
    for (int d=0; d<32; ++d) mu += xr[d];
    mu *= 0.03125f;
    float var = 0.f;
    #pragma unroll
    for (int d=0; d<32; ++d){ float t = xr[d]-mu; var = fmaf(t,t,var); }
    var *= 0.03125f;
    float rs = rsqrtf(var + 1e-5f);
    char* dst = sw + g*2048 + m*128;
    #pragma unroll
    for (int q=0; q<8; ++q){
      u32x4 pv;
      #pragma unroll
      for (int i=0;i<4;++i){
        int d = 4*q+i;
        pv[i] = pk32((xr[d]-mu)*rs*ln_g[d] + ln_b[d]);
      }
      *(u32x4*)(dst + ((q*16) ^ xorm)) = pv;
    }
  }
  asm volatile("" ::: "memory");

  // ---- Phase C: kq = x@wfuse, v = x@wv^T ; kq -> R0 (packed), v^T -> VT (single bf16) ----
  FragU kqh[4], kql[4];
  {
    unsigned int xr8[4][8];
    #pragma unroll
    for (int bt=0; bt<4; ++bt){
      const char* base = sw + bt*2048 + m*128;
      *(u32x4*)&xr8[bt][0] = *(const u32x4*)(base + ((g*32)    ^ xorm));
      *(u32x4*)&xr8[bt][4] = *(const u32x4*)(base + ((g*32+16) ^ xorm));
    }
    asm volatile("" ::: "memory");
    WPair wf0 = load_pre(ws, 0, l), wf1 = load_pre(ws, 1, l);
    WPair wv0 = load_pre(ws, 2, l), wv1 = load_pre(ws, 3, l);
    #pragma unroll
    for (int bt=0; bt<4; ++bt){
      FragU xh, xl; unpack8(xr8[bt], xh, xl);
      f32x4 z = {0,0,0,0};
      f32x4 k0 = mfma3(xh.f, xl.f, wf0.h, wf0.l, z);
      f32x4 k1 = mfma3(xh.f, xl.f, wf1.h, wf1.l, z);
      f32x4 v0 = mfma3(xh.f, xl.f, wv0.h, wv0.l, z);
      f32x4 v1 = mfma3(xh.f, xl.f, wv1.h, wv1.l, z);
      #pragma unroll
      for (int r=0; r<4; ++r){
        int row = 4*g + r;
        int xr_ = (row & 7) << 4;
        char* kb = sw + bt*2048 + row*128;
        *(unsigned int*)(kb + ((4*m)      ^ xr_)) = pk32(k0[r]);
        *(unsigned int*)(kb + ((4*(m+16)) ^ xr_)) = pk32(k1[r]);
      }
      ushort4 pv0, pv1;
      pv0.x=rne1(v0[0]); pv0.y=rne1(v0[1]); pv0.z=rne1(v0[2]); pv0.w=rne1(v0[3]);
      pv1.x=rne1(v1[0]); pv1.y=rne1(v1[1]); pv1.z=rne1(v1[2]); pv1.w=rne1(v1[3]);
      *(ushort4*)(sw + VTO + m*128      + ((bt*32 + 8*g) ^ xorm)) = pv0;
      *(ushort4*)(sw + VTO + (m+16)*128 + ((bt*32 + 8*g) ^ xorm)) = pv1;
    }
    asm volatile("" ::: "memory");
    // one-time kq B-frags -> registers
    #pragma unroll
    for (int bt=0; bt<4; ++bt){
      const char* base = sw + bt*2048 + m*128;
      unsigned int kr[8];
      *(u32x4*)&kr[0] = *(const u32x4*)(base + ((g*32)    ^ xorm));
      *(u32x4*)&kr[4] = *(const u32x4*)(base + ((g*32+16) ^ xorm));
      unpack8(kr, kqh[bt], kql[bt]);
    }
  }
  asm volatile("" ::: "memory");

  // ---- zero page + h init (R0 region now free) ----
  if (l < 2){ u32x4 z = {0,0,0,0}; *(u32x4*)(sw + ZPGO + l*16) = z; }
  float hreg[8];   // hreg[4T+r] = h[(b=g,s=r)][d=m+16T]
  #pragma unroll
  for (int T=0; T<2; ++T){
    #pragma unroll
    for (int r=0; r<4; ++r){
      float v = slot_mu[r*32 + m + 16*T];
      hreg[4*T+r] = v;
      int row = 4*g + r;
      *(unsigned int*)(sw + row*128 + ((4*(m+16*T)) ^ ((row&7)<<4))) = pk32(v);
    }
  }

  // ---- persistent GRU weight fragments + pre-scaled biases ----
  WPair wihf[6], whhf[6];
  float bihl[6], bhhl[6];
  #pragma unroll
  for (int t=0; t<6; ++t){
    wihf[t] = load_pre(ws, 4+t, l);
    whhf[t] = load_pre(ws, 10+t, l);
    float bsc = (t < 4) ? LOG2E : 2.f*LOG2E;
    bihl[t] = gbih[t*16 + m] * bsc;
    bhhl[t] = gbhh[t*16 + m] * bsc;
  }

  for (int it=0; it<3; ++it){
    asm volatile("" ::: "memory");
    // slots A-frags
    unsigned int sr[8];
    {
      const char* sb = sw + m*128;
      *(u32x4*)&sr[0] = *(const u32x4*)(sb + ((g*32)    ^ xorm));
      *(u32x4*)&sr[4] = *(const u32x4*)(sb + ((g*32+16) ^ xorm));
    }
    FragU sh, sl; unpack8(sr, sh, sl);

    // logits (exp2-domain) = slots @ kq^T ; keep batch g
    f32x4 ls = {0,0,0,0};
    #pragma unroll
    for (int bt=0; bt<4; ++bt){
      f32x4 z = {0,0,0,0};
      f32x4 la = mfma3(sh.f, sl.f, kqh[bt].f, kql[bt].f, z);
      if (bt==0) ls = la;
      else {
        bool take = (g==bt);
        #pragma unroll
        for (int c2=0;c2<4;++c2) ls[c2] = take ? la[c2] : ls[c2];
      }
    }
    // softmax over slots (batch g, token m) -> ATH/ATL u16
    {
      float mx = fmaxf(fmaxf(ls[0],ls[1]), fmaxf(ls[2],ls[3]));
      float e0=fexp2(ls[0]-mx), e1=fexp2(ls[1]-mx), e2=fexp2(ls[2]-mx), e3=fexp2(ls[3]-mx);
      float inv = frcp(e0+e1+e2+e3);
      float ev[4] = { e0*inv, e1*inv, e2*inv, e3*inv };
      #pragma unroll
      for (int s=0; s<4; ++s){
        unsigned short h, lo;
        trsplit(ev[s], h, lo);
        *(unsigned short*)(sw + ATO       + g*128 + s*32 + 2*m) = h;
        *(unsigned short*)(sw + ATO + 512 + g*128 + s*32 + 2*m) = lo;
      }
    }
    asm volatile("" ::: "memory");

    // updates^T = v^T @ attn^T : 2 batches packed per MFMA (K=32), v single-bf16
    FragU abh[2], abl[2];
    #pragma unroll
    for (int inst=0; inst<2; ++inst){
      int bk = inst*2 + (g>>1);
      bool match = ((m>>2) == bk);
      int aoff = (m>>2)*128 + (m&3)*32 + (g&1)*16;
      abh[inst].u4 = *(const u32x4*)(match ? (sw + ATO       + aoff) : (sw + ZPGO));
      abl[inst].u4 = *(const u32x4*)(match ? (sw + ATO + 512 + aoff) : (sw + ZPGO));
    }
    f32x4 uT[2];
    #pragma unroll
    for (int T=0; T<2; ++T){
      f32x4 acc = {0,0,0,0};
      #pragma unroll
      for (int inst=0; inst<2; ++inst){
        int bk = inst*2 + (g>>1);
        FragU va;
        va.u4 = *(const u32x4*)(sw + VTO + (16*T+m)*128 + ((bk*32 + (g&1)*16) ^ xorm));
        acc = MFMA16(va.f, abh[inst].f, acc);
        acc = MFMA16(va.f, abl[inst].f, acc);
      }
      uT[T] = acc;
    }
    // u writeback: lane holds upd[(b,s)=m][d=16T+4g+r] -> packed u32, b128
    #pragma unroll
    for (int T=0; T<2; ++T){
      u32x4 up;
      #pragma unroll
      for (int r=0;r<4;++r) up[r] = pk32(uT[T][r]);
      *(u32x4*)(sw + UOF + m*128 + ((64*T + 16*g) ^ xorm)) = up;
    }
    asm volatile("" ::: "memory");

    // u A-frags
    unsigned int ur2[8];
    {
      const char* ub = sw + UOF + m*128;
      *(u32x4*)&ur2[0] = *(const u32x4*)(ub + ((g*32)    ^ xorm));
      *(u32x4*)&ur2[4] = *(const u32x4*)(ub + ((g*32+16) ^ xorm));
    }
    FragU uh, ul; unpack8(ur2, uh, ul);

    // GRU per output half T (tiles t = {T, 2+T, 4+T})
    bool last = (it==2);
    #pragma unroll
    for (int T=0; T<2; ++T){
      f32x4 gi3[3], gh3[3];
      #pragma unroll
      for (int s3=0; s3<3; ++s3){
        int t = 2*s3 + T;
        f32x4 ci = { bihl[t], bihl[t], bihl[t], bihl[t] };
        gi3[s3] = mfma3(uh.f, ul.f, wihf[t].h, wihf[t].l, ci);
        f32x4 ch = { bhhl[t], bhhl[t], bhhl[t], bhhl[t] };
        gh3[s3] = mfma3(sh.f, sl.f, whhf[t].h, whhf[t].l, ch);
      }
      #pragma unroll
      for (int r=0; r<4; ++r){
        // pre-activations already in exp2 domain (r,z x LOG2E; n x 2LOG2E)
        float rr = frcp(1.f + fexp2(-(gi3[0][r] + gh3[0][r])));
        float zz = frcp(1.f + fexp2(-(gi3[1][r] + gh3[1][r])));
        float pre = fmaf(rr, gh3[2][r], gi3[2][r]);
        float nn = fmaf(-2.f, frcp(fexp2(pre) + 1.f), 1.f);
        int d = m + 16*T;
        float hval = hreg[4*T+r];
        float hnew = fmaf(zz, hval - nn, nn);
        hreg[4*T+r] = hnew;
        if (last){
          out[(size_t)(batch0+g)*128 + r*32 + d] = hnew;
        } else {
          int row = 4*g + r;
          *(unsigned int*)(sw + row*128 + ((4*d) ^ ((row&7)<<4))) = pk32(hnew);
        }
      }
    }
  }
}

extern "C" void kernel_launch(void* const* d_in, const int* in_sizes, int n_in,
                              void* d_out, int out_size, void* d_ws, size_t ws_size,
                              hipStream_t stream) {
  const float* latent  = (const float*)d_in[0];
  const float* slot_mu = (const float*)d_in[1];
  const float* w_in    = (const float*)d_in[2];
  const float* b_in    = (const float*)d_in[3];
  const float* ln_g    = (const float*)d_in[4];
  const float* ln_b    = (const float*)d_in[5];
  const float* wq      = (const float*)d_in[6];
  const float* wk      = (const float*)d_in[7];
  const float* wv      = (const float*)d_in[8];
  const float* gwih    = (const float*)d_in[9];
  const float* gwhh    = (const float*)d_in[10];
  const float* gbih    = (const float*)d_in[11];
  const float* gbhh    = (const float*)d_in[12];
  float* out = (float*)d_out;
  unsigned int* ws = (unsigned int*)d_ws;

  prep_kernel<<<1, 1024, 0, stream>>>(wq, wk, wv, gwih, gwhh, ws);

  const int B = in_sizes[0] >> 7;    // 65536
  const int grid = B >> 2;           // 16384 blocks x 64 threads (1 wave, 4 batches)
  slotattn_mfma<<<grid, 64, 0, stream>>>(latent, slot_mu, w_in, b_in, ln_g, ln_b,
                                         gbih, gbhh, ws, out);
}